// Round 12
// baseline (260.412 us; speedup 1.0000x reference)
//
#include <hip/hip_runtime.h>

#define F1 256          // 2*NINP
#define F0 128          // NINP
#define NHE_C 100000    // N_HYPEREDGES
#define BSH 9           // bucket shift: 512 targets per bucket
#define NBUK_MAX 512
#define CHA 8192        // virtual edges per block in scatter pass
#define CAP 10240       // fixed bucket capacity (expected max fill 8192; 22-sigma slack)

typedef short bf16x8 __attribute__((ext_vector_type(8)));
typedef float f32x4 __attribute__((ext_vector_type(4)));

// ---------------- bf16 helpers (RNE) ----------------
__device__ __forceinline__ unsigned short f2bf(float f) {
    unsigned int u = __float_as_uint(f);
    u = (u + 0x7fffu + ((u >> 16) & 1u)) >> 16;
    return (unsigned short)u;
}
__device__ __forceinline__ unsigned int pack2(float a, float b) {
    return (unsigned int)f2bf(a) | ((unsigned int)f2bf(b) << 16);
}
__device__ __forceinline__ void bf2x(unsigned int u, float& a, float& b) {
    a = __uint_as_float(u << 16);
    b = __uint_as_float(u & 0xffff0000u);
}

// ---------------------------------------------------------------------------
// virtual edge stream
// ---------------------------------------------------------------------------
__device__ __forceinline__ void vedge(int v, int E, int EH, int M, int NHE,
                                      const int* __restrict__ src,
                                      const int* __restrict__ dst,
                                      const int* __restrict__ nidx,
                                      const int* __restrict__ hidx,
                                      int& tgt, int& val) {
    if (v < E) { tgt = dst[v]; val = src[v]; }
    else if (v < E + EH) { int e = v - E; tgt = M + hidx[e]; val = nidx[e]; }
    else { int e = v - E - EH; tgt = M + NHE + nidx[e]; val = hidx[e]; }
}

// ---------------------------------------------------------------------------
// prep: all three weight transposes (f32 -> bf16 W^T) + gcur init, one launch
//   seg0: W1 [128x256], seg1: W2 [256x128], seg2: W4 [128x128], seg3: gcur
// ---------------------------------------------------------------------------
__global__ __launch_bounds__(256) void prep_kernel(const float* __restrict__ W1,
                                                   const float* __restrict__ W2,
                                                   const float* __restrict__ W4,
                                                   unsigned short* __restrict__ W1T,
                                                   unsigned short* __restrict__ W2T,
                                                   unsigned short* __restrict__ W4T,
                                                   int* __restrict__ gcur, int nbuk) {
    int t = blockIdx.x * 256 + threadIdx.x;
    if (t < 32768) {                       // W1: K=128, N=256
        int k = t >> 8, n = t & 255;
        W1T[n * 128 + k] = f2bf(W1[t]);
    } else if (t < 65536) {                // W2: K=256, N=128
        int i = t - 32768;
        int k = i >> 7, n = i & 127;
        W2T[n * 256 + k] = f2bf(W2[i]);
    } else if (t < 81920) {                // W4: K=128, N=128
        int i = t - 65536;
        int k = i >> 7, n = i & 127;
        W4T[n * 128 + k] = f2bf(W4[i]);
    } else {
        int b = t - 81920;
        if (b < nbuk) gcur[b] = b * CAP;
    }
}

// 1024-thread blocks: 16 waves/CU for latency hiding
__global__ __launch_bounds__(1024) void bucket_scatter(const int* __restrict__ src,
                                                       const int* __restrict__ dst,
                                                       const int* __restrict__ nidx,
                                                       const int* __restrict__ hidx,
                                                       int* __restrict__ gcur,
                                                       unsigned int* __restrict__ S,
                                                       int E, int EH, int M, int NHE,
                                                       int TE, int nbuk) {
    __shared__ int h[NBUK_MAX];
    __shared__ int bs[NBUK_MAX];
    for (int i = threadIdx.x; i < nbuk; i += 1024) h[i] = 0;
    __syncthreads();
    int base = blockIdx.x * CHA;
    int lim = min(base + CHA, TE);
    for (int v = base + (int)threadIdx.x; v < lim; v += 1024) {
        int tgt, val;
        vedge(v, E, EH, M, NHE, src, dst, nidx, hidx, tgt, val);
        atomicAdd(&h[tgt >> BSH], 1);
    }
    __syncthreads();
    for (int i = threadIdx.x; i < nbuk; i += 1024) {
        if (h[i]) bs[i] = atomicAdd(&gcur[i], h[i]);
        h[i] = 0;
    }
    __syncthreads();
    for (int v = base + (int)threadIdx.x; v < lim; v += 1024) {
        int tgt, val;
        vedge(v, E, EH, M, NHE, src, dst, nidx, hidx, tgt, val);
        int b = tgt >> BSH;
        int off = atomicAdd(&h[b], 1);
        S[bs[b] + off] = ((unsigned int)(tgt & ((1 << BSH) - 1)) << 17) | (unsigned int)val;
    }
}

// 512-thread blocks; direct 512-wide scan
__global__ __launch_bounds__(512) void bucket_build(const unsigned int* __restrict__ S,
                                                    const int* __restrict__ gcur,
                                                    int2* __restrict__ rowBE,
                                                    int* __restrict__ adj,
                                                    float* __restrict__ dis,
                                                    float* __restrict__ Binv,
                                                    float* __restrict__ Dinv,
                                                    int M, int NHE, int NC) {
    __shared__ int hist[512];
    __shared__ int sh[512];
    __shared__ int cur[512];
    int b = blockIdx.x;
    int wsS = b * CAP;
    int weS = gcur[b];
    int t = threadIdx.x;
    hist[t] = 0;
    __syncthreads();
    for (int i = wsS + t; i < weS; i += 512)
        atomicAdd(&hist[S[i] >> 17], 1);
    __syncthreads();
    int c = hist[t];
    sh[t] = c;
    __syncthreads();
    for (int o = 1; o < 512; o <<= 1) {
        int v = (t >= o) ? sh[t - o] : 0;
        __syncthreads();
        sh[t] += v;
        __syncthreads();
    }
    int excl = sh[t] - c;
    cur[t] = excl;
    int tbase = b << BSH;
    int t0 = tbase + t;
    if (t0 < NC) {
        int beg = wsS + excl;
        rowBE[t0] = make_int2(beg, beg + c);
        if (t0 < M)            dis[t0] = rsqrtf((float)c + 1.0f);
        else if (t0 < M + NHE) Binv[t0 - M] = (c > 0) ? 1.0f / (float)c : 0.0f;
        else                   Dinv[t0 - M - NHE] = (c > 0) ? 1.0f / (float)c : 0.0f;
    }
    __syncthreads();
    for (int i = wsS + t; i < weS; i += 512) {
        unsigned int p = S[i];
        int lt = p >> 17;
        int pos = atomicAdd(&cur[lt], 1);
        adj[wsS + pos] = (int)(p & 0x1FFFFu);
    }
}

// ---------------------------------------------------------------------------
// embs[i,f] = bf16( emb[i,f] * dis[i] )
// ---------------------------------------------------------------------------
__global__ __launch_bounds__(256) void scale_to_bf(const float* __restrict__ emb,
                                                   const float* __restrict__ dis,
                                                   unsigned short* __restrict__ out,
                                                   int M) {
    int t = blockIdx.x * 256 + threadIdx.x;
    if (t >= M * (F0 / 4)) return;
    int row = t / (F0 / 4);
    float d = dis[row];
    float4 v = ((const float4*)emb)[t];
    uint2 u;
    u.x = pack2(v.x * d, v.y * d);
    u.y = pack2(v.z * d, v.w * d);
    ((uint2*)out)[t] = u;
}

// ---------------------------------------------------------------------------
// High-occupancy MFMA GEMM (unchanged from R9/R10)
// ---------------------------------------------------------------------------
template<int K, int BN>
__global__ __launch_bounds__(256) void gemm_mfma_g(const unsigned short* __restrict__ A,
                                                   const unsigned short* __restrict__ WT,
                                                   unsigned short* __restrict__ Y,
                                                   int M, int N,
                                                   const float* __restrict__ rowscale) {
    constexpr int NF = BN / 16;
    constexpr int S = K / 32;
    __shared__ unsigned short Ws[BN * K];
    int r0 = blockIdx.x * 64;
    int c0 = blockIdx.y * BN;
    int tid = threadIdx.x;

    constexpr int IT = BN * K / 8 / 256;
#pragma unroll
    for (int it = 0; it < IT; ++it) {
        int i = it * 256 + tid;
        int n = i / (K / 8);
        int k8 = (i % (K / 8)) * 8;
        uint4 v = *(const uint4*)(WT + (size_t)(c0 + n) * K + k8);
        unsigned int boff = ((unsigned int)(n * K + k8) * 2u) ^ ((n & 7) << 4);
        *(uint4*)((char*)Ws + boff) = v;
    }
    __syncthreads();

    int w = tid >> 6, l = tid & 63;
    int lr = l & 15, lk = l >> 4;
    int arow = r0 + w * 16 + lr;
    bool avalid = arow < M;
    const unsigned short* aptr = A + (size_t)arow * K + lk * 8;

    f32x4 acc[NF];
#pragma unroll
    for (int nf = 0; nf < NF; ++nf) acc[nf] = (f32x4){0.f, 0.f, 0.f, 0.f};

    for (int s = 0; s < S; ++s) {
        bf16x8 a = {};
        if (avalid) a = *(const bf16x8*)(aptr + s * 32);
#pragma unroll
        for (int nf = 0; nf < NF; ++nf) {
            int n = nf * 16 + lr;
            unsigned int boff = ((unsigned int)(n * K + s * 32 + lk * 8) * 2u) ^ ((n & 7) << 4);
            bf16x8 b = *(const bf16x8*)((const char*)Ws + boff);
            acc[nf] = __builtin_amdgcn_mfma_f32_16x16x32_bf16(a, b, acc[nf], 0, 0, 0);
        }
    }

    int rowb = r0 + w * 16 + lk * 4;
#pragma unroll
    for (int r = 0; r < 4; ++r) {
        int row = rowb + r;
        if (row < M) {
            float rs = rowscale ? rowscale[row] : 1.0f;
#pragma unroll
            for (int nf = 0; nf < NF; ++nf)
                Y[(size_t)row * N + c0 + nf * 16 + lr] = f2bf(acc[nf][r] * rs);
        }
    }
}

// ---------------------------------------------------------------------------
// Plain gather (bf16 out), rowBE int2 CSR, 8-deep unroll
// ---------------------------------------------------------------------------
template<int F, bool GCN>
__global__ __launch_bounds__(256) void gather_bf(const unsigned short* __restrict__ rows,
                                                 const float* __restrict__ scale,
                                                 const int2* __restrict__ rowBE,
                                                 const int* __restrict__ adj,
                                                 unsigned short* __restrict__ out, int N) {
    constexpr int LANES = (F == 256) ? 64 : 32;
    constexpr int RPB = 256 / LANES;
    int g = threadIdx.x / LANES;
    int lane = threadIdx.x % LANES;
    int seg = blockIdx.x * RPB + g;
    if (seg >= N) return;
    int f0 = lane * 4;
    float acc[4];
    if constexpr (GCN) {
        uint2 u = *(const uint2*)(rows + (size_t)seg * F + f0);
        bf2x(u.x, acc[0], acc[1]); bf2x(u.y, acc[2], acc[3]);
    } else {
        acc[0] = acc[1] = acc[2] = acc[3] = 0.f;
    }

    auto addrow = [&](int s) {
        uint2 u = *(const uint2*)(rows + (size_t)s * F + f0);
        float a, b, c, d;
        bf2x(u.x, a, b); bf2x(u.y, c, d);
        acc[0] += a; acc[1] += b; acc[2] += c; acc[3] += d;
    };

    int2 be = rowBE[seg];
    int k = be.x, end = be.y;
    for (; k + 8 <= end; k += 8) {
        int s0 = adj[k], s1 = adj[k + 1], s2 = adj[k + 2], s3 = adj[k + 3];
        int s4 = adj[k + 4], s5 = adj[k + 5], s6 = adj[k + 6], s7 = adj[k + 7];
        addrow(s0); addrow(s1); addrow(s2); addrow(s3);
        addrow(s4); addrow(s5); addrow(s6); addrow(s7);
    }
    for (; k < end; ++k) addrow(adj[k]);

    float sc = scale[seg];
    uint2 v; v.x = pack2(acc[0] * sc, acc[1] * sc); v.y = pack2(acc[2] * sc, acc[3] * sc);
    *(uint2*)(out + (size_t)seg * F + f0) = v;
}

// ---------------------------------------------------------------------------
// Fused gather + LayerNorm (rowBE int2 CSR), 8-deep unroll
// ---------------------------------------------------------------------------
template<int F, bool GCN>
__global__ __launch_bounds__(256) void gather_ln(const unsigned short* __restrict__ rows,
                                                 const float* __restrict__ scale,
                                                 const int2* __restrict__ rowBE,
                                                 const int* __restrict__ adj,
                                                 const float* __restrict__ bias,
                                                 const float* __restrict__ gamma,
                                                 const float* __restrict__ beta,
                                                 float* __restrict__ out32,
                                                 unsigned short* __restrict__ out16,
                                                 int M) {
    constexpr int LANES = (F == 256) ? 64 : 32;
    constexpr int RPB = 256 / LANES;
    int g = threadIdx.x / LANES;
    int lane = threadIdx.x % LANES;
    int row = blockIdx.x * RPB + g;
    if (row >= M) return;
    int f0 = lane * 4;

    float acc[4];
    if constexpr (GCN) {
        uint2 u = *(const uint2*)(rows + (size_t)row * F + f0);
        bf2x(u.x, acc[0], acc[1]); bf2x(u.y, acc[2], acc[3]);
    } else {
        acc[0] = acc[1] = acc[2] = acc[3] = 0.f;
    }

    auto addrow = [&](int s) {
        uint2 u = *(const uint2*)(rows + (size_t)s * F + f0);
        float a, b, c, d;
        bf2x(u.x, a, b); bf2x(u.y, c, d);
        acc[0] += a; acc[1] += b; acc[2] += c; acc[3] += d;
    };

    int2 be = rowBE[row];
    int k = be.x, end = be.y;
    for (; k + 8 <= end; k += 8) {
        int s0 = adj[k], s1 = adj[k + 1], s2 = adj[k + 2], s3 = adj[k + 3];
        int s4 = adj[k + 4], s5 = adj[k + 5], s6 = adj[k + 6], s7 = adj[k + 7];
        addrow(s0); addrow(s1); addrow(s2); addrow(s3);
        addrow(s4); addrow(s5); addrow(s6); addrow(s7);
    }
    for (; k < end; ++k) addrow(adj[k]);

    float sc = scale[row];
    float4 bb = *(const float4*)(bias + f0);
    float v0 = acc[0] * sc + bb.x;
    float v1 = acc[1] * sc + bb.y;
    float v2 = acc[2] * sc + bb.z;
    float v3 = acc[3] * sc + bb.w;

    float sum = v0 + v1 + v2 + v3;
    float sumsq = v0 * v0 + v1 * v1 + v2 * v2 + v3 * v3;
#pragma unroll
    for (int o = LANES / 2; o > 0; o >>= 1) {
        sum += __shfl_xor(sum, o, 64);
        sumsq += __shfl_xor(sumsq, o, 64);
    }
    float mean = sum / F;
    float var = sumsq / F - mean * mean;
    float inv = rsqrtf(var + 1e-5f);

    float4 gg = *(const float4*)(gamma + f0);
    float4 be4 = *(const float4*)(beta + f0);
    float r0 = (v0 - mean) * inv * gg.x + be4.x;
    float r1 = (v1 - mean) * inv * gg.y + be4.y;
    float r2 = (v2 - mean) * inv * gg.z + be4.z;
    float r3 = (v3 - mean) * inv * gg.w + be4.w;

    if (out32)
        *(float4*)(out32 + (size_t)row * F + f0) = make_float4(r0, r1, r2, r3);
    if (out16) {
        uint2 u; u.x = pack2(r0, r1); u.y = pack2(r2, r3);
        *(uint2*)(out16 + (size_t)row * F + f0) = u;
    }
}

// ---------------------------------------------------------------------------
// Standalone LayerNorm (bf16 in, + bias)
// ---------------------------------------------------------------------------
template<int F>
__global__ __launch_bounds__(256) void ln_bf(const unsigned short* __restrict__ in,
                                             const float* __restrict__ bias,
                                             const float* __restrict__ gamma,
                                             const float* __restrict__ beta,
                                             unsigned short* __restrict__ out16, int M) {
    int wave = threadIdx.x >> 6;
    int lane = threadIdx.x & 63;
    int row = blockIdx.x * 4 + wave;
    if (row >= M) return;
    int f0 = lane * 4;

    uint2 u = *(const uint2*)(in + (size_t)row * F + f0);
    float v0, v1, v2, v3;
    bf2x(u.x, v0, v1); bf2x(u.y, v2, v3);
    float4 bb = *(const float4*)(bias + f0);
    v0 += bb.x; v1 += bb.y; v2 += bb.z; v3 += bb.w;

    float sum = v0 + v1 + v2 + v3;
    float sumsq = v0 * v0 + v1 * v1 + v2 * v2 + v3 * v3;
#pragma unroll
    for (int o = 32; o > 0; o >>= 1) {
        sum += __shfl_xor(sum, o, 64);
        sumsq += __shfl_xor(sumsq, o, 64);
    }
    float mean = sum / F;
    float var = sumsq / F - mean * mean;
    float inv = rsqrtf(var + 1e-5f);

    float4 gg = *(const float4*)(gamma + f0);
    float4 be = *(const float4*)(beta + f0);
    float r0 = (v0 - mean) * inv * gg.x + be.x;
    float r1 = (v1 - mean) * inv * gg.y + be.y;
    float r2 = (v2 - mean) * inv * gg.z + be.z;
    float r3 = (v3 - mean) * inv * gg.w + be.w;

    uint2 o2; o2.x = pack2(r0, r1); o2.y = pack2(r2, r3);
    *(uint2*)(out16 + (size_t)row * F + f0) = o2;
}

// ---------------------------------------------------------------------------
extern "C" void kernel_launch(void* const* d_in, const int* in_sizes, int n_in,
                              void* d_out, int out_size, void* d_ws, size_t ws_size,
                              hipStream_t stream) {
    const float* emb    = (const float*)d_in[0];
    const float* W1     = (const float*)d_in[1];
    const float* b1     = (const float*)d_in[2];
    const float* gamma1 = (const float*)d_in[3];
    const float* beta1  = (const float*)d_in[4];
    const float* W2     = (const float*)d_in[5];
    const float* b2     = (const float*)d_in[6];
    const float* gamma2 = (const float*)d_in[7];
    const float* beta2  = (const float*)d_in[8];
    const float* W4     = (const float*)d_in[9];
    const float* b4     = (const float*)d_in[10];
    const float* gamma4 = (const float*)d_in[11];
    const float* beta4  = (const float*)d_in[12];
    const int* heter    = (const int*)d_in[13];
    const int* nidx     = (const int*)d_in[14];
    const int* hidx     = (const int*)d_in[15];

    const int M   = in_sizes[0] / F0;   // 50000 nodes
    const int E   = in_sizes[13] / 2;   // 800000 heter edges
    const int EH  = in_sizes[14];       // 800000 hyper incidences
    const int NHE = NHE_C;              // 100000

    const int* src = heter;
    const int* dst = heter + E;

    const int NC = M + NHE + M;         // 200000 combined targets
    const int TE = E + 2 * EH;          // 2.4M combined incidences
    const int nbuk = (NC + (1 << BSH) - 1) >> BSH;   // 391

    // ---- workspace layout (bytes) ----
    char* w = (char*)d_ws;
    unsigned short* B0 = (unsigned short*)w;                 // 25.6 MB: g [M,128] -> ef [NHE,128]
    unsigned short* B1 = (unsigned short*)(w + 25600000);    // 12.8 MB: embs -> xws2 -> xw4
    float* dis  = (float*)(w + 38400000);                    // M
    float* Dinv = (float*)(w + 38600000);                    // M
    float* Binv = (float*)(w + 38800000);                    // NHE
    int*   iw   = (int*)(w + 39200000);
    int2* rowBE = (int2*)iw;                         // NC int2
    int* adjAll = iw + 2 * 200000;                   // nbuk*CAP
    int* gcur   = iw + 2 * 200000 + 391 * CAP;       // nbuk
    unsigned short* W1T = (unsigned short*)(w + 56900000);   // [256][128]
    unsigned short* W2T = (unsigned short*)(w + 56965536);   // [128][256]
    unsigned short* W4T = (unsigned short*)(w + 57031072);   // [128][128]

    // d_out scratch plan:
    float* dout0 = (float*)d_out;                                      // heter f32 [M,128] (final)
    float* dout1 = (float*)((char*)d_out + 25600000);                  // hyper f32 [M,128] (final)
    unsigned short* h1  = (unsigned short*)d_out;                      // GEMM1/LN1 bf16 [M,256] (lower)
    unsigned short* hbf = (unsigned short*)((char*)d_out + 25600000);  // LN2 out bf16 [M,128] (upper)
    unsigned int*   S   = (unsigned int*)((char*)d_out + 25600000);    // bucketed payload 16 MB (upper, dead early)

    const int2* rpG = rowBE;
    const int2* rpH = rowBE + M;
    const int2* rpN = rowBE + M + NHE;

    const int NBA = (TE + CHA - 1) / CHA;
    const int MB64 = (M + 63) / 64;

    // ---- prep: W transposes + gcur init (one launch) ----
    prep_kernel<<<dim3((81920 + nbuk + 255) / 256), 256, 0, stream>>>(
        W1, W2, W4, W1T, W2T, W4T, gcur, nbuk);

    // ---- single-pass bucketed CSR build ----
    bucket_scatter<<<dim3(NBA), 1024, 0, stream>>>(src, dst, nidx, hidx, gcur, S, E, EH, M, NHE, TE, nbuk);
    bucket_build<<<dim3(nbuk), 512, 0, stream>>>(S, gcur, rowBE, adjAll, dis, Binv, Dinv, M, NHE, NC);

    // ---- conv1 (aggregate-first) ----
    scale_to_bf<<<dim3((M * (F0 / 4) + 255) / 256), 256, 0, stream>>>(emb, dis, B1, M);
    gather_bf<F0, true><<<dim3((M + 7) / 8), 256, 0, stream>>>(B1, dis, rpG, adjAll, B0, M);
    gemm_mfma_g<128, 128><<<dim3(MB64, 2), 256, 0, stream>>>(B0, W1T, h1, M, F1, nullptr);
    ln_bf<F1><<<dim3((M + 3) / 4), 256, 0, stream>>>(h1, b1, gamma1, beta1, h1, M);

    // ---- conv2 ----
    gemm_mfma_g<256, 64><<<dim3(MB64, 2), 256, 0, stream>>>(h1, W2T, B1, M, F0, dis);
    gather_ln<F0, true><<<dim3((M + 7) / 8), 256, 0, stream>>>(B1, dis, rpG, adjAll,
                                                               b2, gamma2, beta2,
                                                               dout0, hbf, M);

    // ---- hyper branch ----
    gemm_mfma_g<128, 128><<<dim3(MB64, 1), 256, 0, stream>>>(hbf, W4T, B1, M, F0, nullptr);
    gather_bf<F0, false><<<dim3((NHE + 7) / 8), 256, 0, stream>>>(B1, Binv, rpH, adjAll, B0, NHE);
    gather_ln<F0, false><<<dim3((M + 7) / 8), 256, 0, stream>>>(B0, Dinv, rpN, adjAll,
                                                                b4, gamma4, beta4,
                                                                dout1, nullptr, M);
}

// Round 13
// 251.520 us; speedup vs baseline: 1.0354x; 1.0354x over previous
//
#include <hip/hip_runtime.h>

#define F1 256          // 2*NINP
#define F0 128          // NINP
#define NHE_C 100000    // N_HYPEREDGES
#define BSH 9           // bucket shift: 512 targets per bucket
#define NBUK_MAX 512
#define CHA 8192        // virtual edges per block in scatter pass
#define CAP 10240       // fixed bucket capacity (expected max fill 8192; 22-sigma slack)

typedef short bf16x8 __attribute__((ext_vector_type(8)));
typedef float f32x4 __attribute__((ext_vector_type(4)));

// ---------------- bf16 helpers (RNE) ----------------
__device__ __forceinline__ unsigned short f2bf(float f) {
    unsigned int u = __float_as_uint(f);
    u = (u + 0x7fffu + ((u >> 16) & 1u)) >> 16;
    return (unsigned short)u;
}
__device__ __forceinline__ unsigned int pack2(float a, float b) {
    return (unsigned int)f2bf(a) | ((unsigned int)f2bf(b) << 16);
}
__device__ __forceinline__ void bf2x(unsigned int u, float& a, float& b) {
    a = __uint_as_float(u << 16);
    b = __uint_as_float(u & 0xffff0000u);
}

// ---------------------------------------------------------------------------
// virtual edge stream
// ---------------------------------------------------------------------------
__device__ __forceinline__ void vedge(int v, int E, int EH, int M, int NHE,
                                      const int* __restrict__ src,
                                      const int* __restrict__ dst,
                                      const int* __restrict__ nidx,
                                      const int* __restrict__ hidx,
                                      int& tgt, int& val) {
    if (v < E) { tgt = dst[v]; val = src[v]; }
    else if (v < E + EH) { int e = v - E; tgt = M + hidx[e]; val = nidx[e]; }
    else { int e = v - E - EH; tgt = M + NHE + nidx[e]; val = hidx[e]; }
}

// ---------------------------------------------------------------------------
// prep: weight transposes (f32 -> bf16 W^T) + gcur init, one launch
// ---------------------------------------------------------------------------
__global__ __launch_bounds__(256) void prep_kernel(const float* __restrict__ W1,
                                                   const float* __restrict__ W2,
                                                   const float* __restrict__ W4,
                                                   unsigned short* __restrict__ W1T,
                                                   unsigned short* __restrict__ W2T,
                                                   unsigned short* __restrict__ W4T,
                                                   int* __restrict__ gcur, int nbuk) {
    int t = blockIdx.x * 256 + threadIdx.x;
    if (t < 32768) {                       // W1: K=128, N=256
        int k = t >> 8, n = t & 255;
        W1T[n * 128 + k] = f2bf(W1[t]);
    } else if (t < 65536) {                // W2: K=256, N=128
        int i = t - 32768;
        int k = i >> 7, n = i & 127;
        W2T[n * 256 + k] = f2bf(W2[i]);
    } else if (t < 81920) {                // W4: K=128, N=128
        int i = t - 65536;
        int k = i >> 7, n = i & 127;
        W4T[n * 128 + k] = f2bf(W4[i]);
    } else {
        int b = t - 81920;
        if (b < nbuk) gcur[b] = b * CAP;
    }
}

// 1024-thread blocks: 16 waves/CU for latency hiding
__global__ __launch_bounds__(1024) void bucket_scatter(const int* __restrict__ src,
                                                       const int* __restrict__ dst,
                                                       const int* __restrict__ nidx,
                                                       const int* __restrict__ hidx,
                                                       int* __restrict__ gcur,
                                                       unsigned int* __restrict__ S,
                                                       int E, int EH, int M, int NHE,
                                                       int TE, int nbuk) {
    __shared__ int h[NBUK_MAX];
    __shared__ int bs[NBUK_MAX];
    for (int i = threadIdx.x; i < nbuk; i += 1024) h[i] = 0;
    __syncthreads();
    int base = blockIdx.x * CHA;
    int lim = min(base + CHA, TE);
    for (int v = base + (int)threadIdx.x; v < lim; v += 1024) {
        int tgt, val;
        vedge(v, E, EH, M, NHE, src, dst, nidx, hidx, tgt, val);
        atomicAdd(&h[tgt >> BSH], 1);
    }
    __syncthreads();
    for (int i = threadIdx.x; i < nbuk; i += 1024) {
        if (h[i]) bs[i] = atomicAdd(&gcur[i], h[i]);
        h[i] = 0;
    }
    __syncthreads();
    for (int v = base + (int)threadIdx.x; v < lim; v += 1024) {
        int tgt, val;
        vedge(v, E, EH, M, NHE, src, dst, nidx, hidx, tgt, val);
        int b = tgt >> BSH;
        int off = atomicAdd(&h[b], 1);
        S[bs[b] + off] = ((unsigned int)(tgt & ((1 << BSH) - 1)) << 17) | (unsigned int)val;
    }
}

// 512-thread blocks; adj stores BYTE offsets (val << 8: all gather tables are
// 128-col bf16 = 256 B rows), saving a shift in every gather address calc.
__global__ __launch_bounds__(512) void bucket_build(const unsigned int* __restrict__ S,
                                                    const int* __restrict__ gcur,
                                                    int2* __restrict__ rowBE,
                                                    int* __restrict__ adj,
                                                    float* __restrict__ dis,
                                                    float* __restrict__ Binv,
                                                    float* __restrict__ Dinv,
                                                    int M, int NHE, int NC) {
    __shared__ int hist[512];
    __shared__ int sh[512];
    __shared__ int cur[512];
    int b = blockIdx.x;
    int wsS = b * CAP;
    int weS = gcur[b];
    int t = threadIdx.x;
    hist[t] = 0;
    __syncthreads();
    for (int i = wsS + t; i < weS; i += 512)
        atomicAdd(&hist[S[i] >> 17], 1);
    __syncthreads();
    int c = hist[t];
    sh[t] = c;
    __syncthreads();
    for (int o = 1; o < 512; o <<= 1) {
        int v = (t >= o) ? sh[t - o] : 0;
        __syncthreads();
        sh[t] += v;
        __syncthreads();
    }
    int excl = sh[t] - c;
    cur[t] = excl;
    int tbase = b << BSH;
    int t0 = tbase + t;
    if (t0 < NC) {
        int beg = wsS + excl;
        rowBE[t0] = make_int2(beg, beg + c);
        if (t0 < M)            dis[t0] = rsqrtf((float)c + 1.0f);
        else if (t0 < M + NHE) Binv[t0 - M] = (c > 0) ? 1.0f / (float)c : 0.0f;
        else                   Dinv[t0 - M - NHE] = (c > 0) ? 1.0f / (float)c : 0.0f;
    }
    __syncthreads();
    for (int i = wsS + t; i < weS; i += 512) {
        unsigned int p = S[i];
        int lt = p >> 17;
        int pos = atomicAdd(&cur[lt], 1);
        adj[wsS + pos] = (int)(p & 0x1FFFFu) << 8;   // byte offset of 256 B row
    }
}

// ---------------------------------------------------------------------------
// embs[i,f] = bf16( emb[i,f] * dis[i] )
// ---------------------------------------------------------------------------
__global__ __launch_bounds__(256) void scale_to_bf(const float* __restrict__ emb,
                                                   const float* __restrict__ dis,
                                                   unsigned short* __restrict__ out,
                                                   int M) {
    int t = blockIdx.x * 256 + threadIdx.x;
    if (t >= M * (F0 / 4)) return;
    int row = t / (F0 / 4);
    float d = dis[row];
    float4 v = ((const float4*)emb)[t];
    uint2 u;
    u.x = pack2(v.x * d, v.y * d);
    u.y = pack2(v.z * d, v.w * d);
    ((uint2*)out)[t] = u;
}

// ---------------------------------------------------------------------------
// High-occupancy MFMA GEMM (unchanged from R9/R10)
// ---------------------------------------------------------------------------
template<int K, int BN>
__global__ __launch_bounds__(256) void gemm_mfma_g(const unsigned short* __restrict__ A,
                                                   const unsigned short* __restrict__ WT,
                                                   unsigned short* __restrict__ Y,
                                                   int M, int N,
                                                   const float* __restrict__ rowscale) {
    constexpr int NF = BN / 16;
    constexpr int S = K / 32;
    __shared__ unsigned short Ws[BN * K];
    int r0 = blockIdx.x * 64;
    int c0 = blockIdx.y * BN;
    int tid = threadIdx.x;

    constexpr int IT = BN * K / 8 / 256;
#pragma unroll
    for (int it = 0; it < IT; ++it) {
        int i = it * 256 + tid;
        int n = i / (K / 8);
        int k8 = (i % (K / 8)) * 8;
        uint4 v = *(const uint4*)(WT + (size_t)(c0 + n) * K + k8);
        unsigned int boff = ((unsigned int)(n * K + k8) * 2u) ^ ((n & 7) << 4);
        *(uint4*)((char*)Ws + boff) = v;
    }
    __syncthreads();

    int w = tid >> 6, l = tid & 63;
    int lr = l & 15, lk = l >> 4;
    int arow = r0 + w * 16 + lr;
    bool avalid = arow < M;
    const unsigned short* aptr = A + (size_t)arow * K + lk * 8;

    f32x4 acc[NF];
#pragma unroll
    for (int nf = 0; nf < NF; ++nf) acc[nf] = (f32x4){0.f, 0.f, 0.f, 0.f};

    for (int s = 0; s < S; ++s) {
        bf16x8 a = {};
        if (avalid) a = *(const bf16x8*)(aptr + s * 32);
#pragma unroll
        for (int nf = 0; nf < NF; ++nf) {
            int n = nf * 16 + lr;
            unsigned int boff = ((unsigned int)(n * K + s * 32 + lk * 8) * 2u) ^ ((n & 7) << 4);
            bf16x8 b = *(const bf16x8*)((const char*)Ws + boff);
            acc[nf] = __builtin_amdgcn_mfma_f32_16x16x32_bf16(a, b, acc[nf], 0, 0, 0);
        }
    }

    int rowb = r0 + w * 16 + lk * 4;
#pragma unroll
    for (int r = 0; r < 4; ++r) {
        int row = rowb + r;
        if (row < M) {
            float rs = rowscale ? rowscale[row] : 1.0f;
#pragma unroll
            for (int nf = 0; nf < NF; ++nf)
                Y[(size_t)row * N + c0 + nf * 16 + lr] = f2bf(acc[nf][r] * rs);
        }
    }
}

// ---------------------------------------------------------------------------
// Plain gather (bf16 out), rowBE int2 CSR, byte-offset adj, 4-deep unroll
// ---------------------------------------------------------------------------
template<int F, bool GCN>
__global__ __launch_bounds__(256) void gather_bf(const unsigned short* __restrict__ rows,
                                                 const float* __restrict__ scale,
                                                 const int2* __restrict__ rowBE,
                                                 const int* __restrict__ adj,
                                                 unsigned short* __restrict__ out, int N) {
    constexpr int LANES = (F == 256) ? 64 : 32;
    constexpr int RPB = 256 / LANES;
    int g = threadIdx.x / LANES;
    int lane = threadIdx.x % LANES;
    int seg = blockIdx.x * RPB + g;
    if (seg >= N) return;
    int f0b = lane * 8;            // byte offset within row (4 bf16)
    const char* base = (const char*)rows;
    float acc[4];
    if constexpr (GCN) {
        uint2 u = *(const uint2*)(base + (size_t)seg * (F * 2) + f0b);
        bf2x(u.x, acc[0], acc[1]); bf2x(u.y, acc[2], acc[3]);
    } else {
        acc[0] = acc[1] = acc[2] = acc[3] = 0.f;
    }

    auto addrow = [&](int soff) {
        uint2 u = *(const uint2*)(base + (size_t)(unsigned int)soff + f0b);
        float a, b, c, d;
        bf2x(u.x, a, b); bf2x(u.y, c, d);
        acc[0] += a; acc[1] += b; acc[2] += c; acc[3] += d;
    };

    int2 be = rowBE[seg];
    int k = be.x, end = be.y;
    for (; k + 4 <= end; k += 4) {
        int s0 = adj[k], s1 = adj[k + 1], s2 = adj[k + 2], s3 = adj[k + 3];
        addrow(s0); addrow(s1); addrow(s2); addrow(s3);
    }
    for (; k < end; ++k) addrow(adj[k]);

    float sc = scale[seg];
    uint2 v; v.x = pack2(acc[0] * sc, acc[1] * sc); v.y = pack2(acc[2] * sc, acc[3] * sc);
    *(uint2*)(out + (size_t)seg * F + lane * 4) = v;
}

// ---------------------------------------------------------------------------
// Fused gather + LayerNorm, byte-offset adj, 4-deep unroll
// ---------------------------------------------------------------------------
template<int F, bool GCN>
__global__ __launch_bounds__(256) void gather_ln(const unsigned short* __restrict__ rows,
                                                 const float* __restrict__ scale,
                                                 const int2* __restrict__ rowBE,
                                                 const int* __restrict__ adj,
                                                 const float* __restrict__ bias,
                                                 const float* __restrict__ gamma,
                                                 const float* __restrict__ beta,
                                                 float* __restrict__ out32,
                                                 unsigned short* __restrict__ out16,
                                                 int M) {
    constexpr int LANES = (F == 256) ? 64 : 32;
    constexpr int RPB = 256 / LANES;
    int g = threadIdx.x / LANES;
    int lane = threadIdx.x % LANES;
    int row = blockIdx.x * RPB + g;
    if (row >= M) return;
    int f0 = lane * 4;
    int f0b = lane * 8;
    const char* base = (const char*)rows;

    float acc[4];
    if constexpr (GCN) {
        uint2 u = *(const uint2*)(base + (size_t)row * (F * 2) + f0b);
        bf2x(u.x, acc[0], acc[1]); bf2x(u.y, acc[2], acc[3]);
    } else {
        acc[0] = acc[1] = acc[2] = acc[3] = 0.f;
    }

    auto addrow = [&](int soff) {
        uint2 u = *(const uint2*)(base + (size_t)(unsigned int)soff + f0b);
        float a, b, c, d;
        bf2x(u.x, a, b); bf2x(u.y, c, d);
        acc[0] += a; acc[1] += b; acc[2] += c; acc[3] += d;
    };

    int2 be = rowBE[row];
    int k = be.x, end = be.y;
    for (; k + 4 <= end; k += 4) {
        int s0 = adj[k], s1 = adj[k + 1], s2 = adj[k + 2], s3 = adj[k + 3];
        addrow(s0); addrow(s1); addrow(s2); addrow(s3);
    }
    for (; k < end; ++k) addrow(adj[k]);

    float sc = scale[row];
    float4 bb = *(const float4*)(bias + f0);
    float v0 = acc[0] * sc + bb.x;
    float v1 = acc[1] * sc + bb.y;
    float v2 = acc[2] * sc + bb.z;
    float v3 = acc[3] * sc + bb.w;

    float sum = v0 + v1 + v2 + v3;
    float sumsq = v0 * v0 + v1 * v1 + v2 * v2 + v3 * v3;
#pragma unroll
    for (int o = LANES / 2; o > 0; o >>= 1) {
        sum += __shfl_xor(sum, o, 64);
        sumsq += __shfl_xor(sumsq, o, 64);
    }
    float mean = sum / F;
    float var = sumsq / F - mean * mean;
    float inv = rsqrtf(var + 1e-5f);

    float4 gg = *(const float4*)(gamma + f0);
    float4 be4 = *(const float4*)(beta + f0);
    float r0 = (v0 - mean) * inv * gg.x + be4.x;
    float r1 = (v1 - mean) * inv * gg.y + be4.y;
    float r2 = (v2 - mean) * inv * gg.z + be4.z;
    float r3 = (v3 - mean) * inv * gg.w + be4.w;

    if (out32)
        *(float4*)(out32 + (size_t)row * F + f0) = make_float4(r0, r1, r2, r3);
    if (out16) {
        uint2 u; u.x = pack2(r0, r1); u.y = pack2(r2, r3);
        *(uint2*)(out16 + (size_t)row * F + f0) = u;
    }
}

// ---------------------------------------------------------------------------
// Standalone LayerNorm (bf16 in, + bias)
// ---------------------------------------------------------------------------
template<int F>
__global__ __launch_bounds__(256) void ln_bf(const unsigned short* __restrict__ in,
                                             const float* __restrict__ bias,
                                             const float* __restrict__ gamma,
                                             const float* __restrict__ beta,
                                             unsigned short* __restrict__ out16, int M) {
    int wave = threadIdx.x >> 6;
    int lane = threadIdx.x & 63;
    int row = blockIdx.x * 4 + wave;
    if (row >= M) return;
    int f0 = lane * 4;

    uint2 u = *(const uint2*)(in + (size_t)row * F + f0);
    float v0, v1, v2, v3;
    bf2x(u.x, v0, v1); bf2x(u.y, v2, v3);
    float4 bb = *(const float4*)(bias + f0);
    v0 += bb.x; v1 += bb.y; v2 += bb.z; v3 += bb.w;

    float sum = v0 + v1 + v2 + v3;
    float sumsq = v0 * v0 + v1 * v1 + v2 * v2 + v3 * v3;
#pragma unroll
    for (int o = 32; o > 0; o >>= 1) {
        sum += __shfl_xor(sum, o, 64);
        sumsq += __shfl_xor(sumsq, o, 64);
    }
    float mean = sum / F;
    float var = sumsq / F - mean * mean;
    float inv = rsqrtf(var + 1e-5f);

    float4 gg = *(const float4*)(gamma + f0);
    float4 be = *(const float4*)(beta + f0);
    float r0 = (v0 - mean) * inv * gg.x + be.x;
    float r1 = (v1 - mean) * inv * gg.y + be.y;
    float r2 = (v2 - mean) * inv * gg.z + be.z;
    float r3 = (v3 - mean) * inv * gg.w + be.w;

    uint2 o2; o2.x = pack2(r0, r1); o2.y = pack2(r2, r3);
    *(uint2*)(out16 + (size_t)row * F + f0) = o2;
}

// ---------------------------------------------------------------------------
extern "C" void kernel_launch(void* const* d_in, const int* in_sizes, int n_in,
                              void* d_out, int out_size, void* d_ws, size_t ws_size,
                              hipStream_t stream) {
    const float* emb    = (const float*)d_in[0];
    const float* W1     = (const float*)d_in[1];
    const float* b1     = (const float*)d_in[2];
    const float* gamma1 = (const float*)d_in[3];
    const float* beta1  = (const float*)d_in[4];
    const float* W2     = (const float*)d_in[5];
    const float* b2     = (const float*)d_in[6];
    const float* gamma2 = (const float*)d_in[7];
    const float* beta2  = (const float*)d_in[8];
    const float* W4     = (const float*)d_in[9];
    const float* b4     = (const float*)d_in[10];
    const float* gamma4 = (const float*)d_in[11];
    const float* beta4  = (const float*)d_in[12];
    const int* heter    = (const int*)d_in[13];
    const int* nidx     = (const int*)d_in[14];
    const int* hidx     = (const int*)d_in[15];

    const int M   = in_sizes[0] / F0;   // 50000 nodes
    const int E   = in_sizes[13] / 2;   // 800000 heter edges
    const int EH  = in_sizes[14];       // 800000 hyper incidences
    const int NHE = NHE_C;              // 100000

    const int* src = heter;
    const int* dst = heter + E;

    const int NC = M + NHE + M;         // 200000 combined targets
    const int TE = E + 2 * EH;          // 2.4M combined incidences
    const int nbuk = (NC + (1 << BSH) - 1) >> BSH;   // 391

    // ---- workspace layout (bytes) ----
    char* w = (char*)d_ws;
    unsigned short* B0 = (unsigned short*)w;                 // 25.6 MB: g [M,128] -> ef [NHE,128]
    unsigned short* B1 = (unsigned short*)(w + 25600000);    // 12.8 MB: embs -> xws2 -> xw4
    float* dis  = (float*)(w + 38400000);                    // M
    float* Dinv = (float*)(w + 38600000);                    // M
    float* Binv = (float*)(w + 38800000);                    // NHE
    int*   iw   = (int*)(w + 39200000);
    int2* rowBE = (int2*)iw;                         // NC int2
    int* adjAll = iw + 2 * 200000;                   // nbuk*CAP
    int* gcur   = iw + 2 * 200000 + 391 * CAP;       // nbuk
    unsigned short* W1T = (unsigned short*)(w + 56900000);   // [256][128]
    unsigned short* W2T = (unsigned short*)(w + 56965536);   // [128][256]
    unsigned short* W4T = (unsigned short*)(w + 57031072);   // [128][128]

    // d_out scratch plan:
    float* dout0 = (float*)d_out;                                      // heter f32 [M,128] (final)
    float* dout1 = (float*)((char*)d_out + 25600000);                  // hyper f32 [M,128] (final)
    unsigned short* h1  = (unsigned short*)d_out;                      // GEMM1/LN1 bf16 [M,256] (lower)
    unsigned short* hbf = (unsigned short*)((char*)d_out + 25600000);  // LN2 out bf16 [M,128] (upper)
    unsigned int*   S   = (unsigned int*)((char*)d_out + 25600000);    // bucketed payload 16 MB (upper, dead early)

    const int2* rpG = rowBE;
    const int2* rpH = rowBE + M;
    const int2* rpN = rowBE + M + NHE;

    const int NBA = (TE + CHA - 1) / CHA;
    const int MB64 = (M + 63) / 64;

    // ---- prep: W transposes + gcur init (one launch) ----
    prep_kernel<<<dim3((81920 + nbuk + 255) / 256), 256, 0, stream>>>(
        W1, W2, W4, W1T, W2T, W4T, gcur, nbuk);

    // ---- single-pass bucketed CSR build ----
    bucket_scatter<<<dim3(NBA), 1024, 0, stream>>>(src, dst, nidx, hidx, gcur, S, E, EH, M, NHE, TE, nbuk);
    bucket_build<<<dim3(nbuk), 512, 0, stream>>>(S, gcur, rowBE, adjAll, dis, Binv, Dinv, M, NHE, NC);

    // ---- conv1 (aggregate-first) ----
    scale_to_bf<<<dim3((M * (F0 / 4) + 255) / 256), 256, 0, stream>>>(emb, dis, B1, M);
    gather_bf<F0, true><<<dim3((M + 7) / 8), 256, 0, stream>>>(B1, dis, rpG, adjAll, B0, M);
    gemm_mfma_g<128, 128><<<dim3(MB64, 2), 256, 0, stream>>>(B0, W1T, h1, M, F1, nullptr);
    ln_bf<F1><<<dim3((M + 3) / 4), 256, 0, stream>>>(h1, b1, gamma1, beta1, h1, M);

    // ---- conv2 ----
    gemm_mfma_g<256, 64><<<dim3(MB64, 2), 256, 0, stream>>>(h1, W2T, B1, M, F0, dis);
    gather_ln<F0, true><<<dim3((M + 7) / 8), 256, 0, stream>>>(B1, dis, rpG, adjAll,
                                                               b2, gamma2, beta2,
                                                               dout0, hbf, M);

    // ---- hyper branch ----
    gemm_mfma_g<128, 128><<<dim3(MB64, 1), 256, 0, stream>>>(hbf, W4T, B1, M, F0, nullptr);
    gather_bf<F0, false><<<dim3((NHE + 7) / 8), 256, 0, stream>>>(B1, Binv, rpH, adjAll, B0, NHE);
    gather_ln<F0, false><<<dim3((M + 7) / 8), 256, 0, stream>>>(B0, Dinv, rpN, adjAll,
                                                                b4, gamma4, beta4,
                                                                dout1, nullptr, M);
}